// Round 24
// baseline (242.462 us; speedup 1.0000x reference)
//
#include <hip/hip_runtime.h>

typedef _Float16 f16;
typedef _Float16 f16x2 __attribute__((ext_vector_type(2)));
typedef _Float16 f16x8 __attribute__((ext_vector_type(8)));
typedef float f32x4 __attribute__((ext_vector_type(4)));
typedef float f32x16 __attribute__((ext_vector_type(16)));

namespace {

constexpr int kC = 16, kN = 8192, kH = 181, kOut = 3;
constexpr int kMB = 64;            // points per block (2x 32-pt tile B-hold)
constexpr int kKpad = 384;
constexpr int kNT = 48;            // 16-wide tiles (L0/final path)
constexpr int kKS = 12;            // k-steps of 32 (L0/final path)
constexpr int kMT = 24;            // 32-wide comp tiles (hidden 32x32 path)
constexpr int kKS2 = 24;           // k-steps of 16 (hidden 32x32 path)
constexpr int kRowB = 784;         // 768 data bytes + 16B pad
constexpr float kOmega = 30.f, kS2 = 100.f;

constexpr size_t kWLayerStride = (size_t)kMT * kKS2 * 64 * 8;  // == 48*12*64*8
constexpr size_t kWfOff = kWLayerStride * kC * 2;
constexpr size_t kWfStride = (size_t)kKS * 64 * 8;
constexpr size_t kW0Off = kWfOff + (size_t)kC * kWfStride;
constexpr size_t kW0Stride = (size_t)kNT * 64 * 8;
constexpr size_t kBiasOff = kW0Off + (size_t)kC * kW0Stride;  // f32x4 per q

__device__ __forceinline__ int xadr(int row, int colb) { return row * kRowB + colb; }

// ---- prep: pack hidden weights into 32x32x16 A-fragment order
// ws[c][L][mt(24)][ks(24)][lane][8]: value = W'[mt*32 + (lane&31)]
// [ks*16 + (lane>>5)*8 + j], W' = real expansion (rows 4o+comp, cols 2i+kodd).
// Also packs bias quads f32x4[q] (zero-padded).
__global__ __launch_bounds__(768) void prep_hidden(
    const int* __restrict__ model_idx, const int* __restrict__ bias_idx,
    const float* __restrict__ W1a, const float* __restrict__ W1b,
    const float* __restrict__ W2a, const float* __restrict__ W2b,
    const float* __restrict__ b1a, const float* __restrict__ b1b,
    const float* __restrict__ b2a, const float* __restrict__ b2b,
    f16* __restrict__ ws)
{
  __shared__ float s[kH][2][8][2];   // [i][branch][osub(8)][reim]
  const int bid = blockIdx.x;
  const int c  = bid / (2 * kMT);
  const int L  = (bid / kMT) % 2;
  const int mt = bid % kMT;
  const int m  = model_idx[c];
  const float* Wa = (L == 0 ? W1a : W2a) + (size_t)m * kH * kH * 2;
  const float* Wb = (L == 0 ? W1b : W2b) + (size_t)m * kH * kH * 2;
  const int t = threadIdx.x;
  if (t < 2 * kH) {
    const int i = t >> 1, br = t & 1;
    const float* base = (br ? Wb : Wa) + (size_t)i * kH * 2;
#pragma unroll
    for (int e = 0; e < 16; ++e) {
      const int osub = e >> 1, reim = e & 1;
      const int o = mt * 8 + osub;
      s[i][br][osub][reim] = (o < kH) ? base[o * 2 + reim] : 0.f;
    }
  }
  if (t < 32) {   // bias quads: q = mt*8 + (t>>2), comp j = t&3
    const int bix = bias_idx[c];
    const float* pa = (L == 0 ? b1a : b2a) + (size_t)bix * kH * 2;
    const float* pb = (L == 0 ? b1b : b2b) + (size_t)bix * kH * 2;
    const int osub = t >> 2, j = t & 3;
    const int q = mt * 8 + osub;
    float v = 0.f;
    if (q < kH) v = (j < 2) ? pa[q * 2 + j] : pb[q * 2 + (j - 2)];
    float* fb = (float*)(ws + kBiasOff);
    fb[((size_t)(c * 2 + L) * 192 + mt * 8) * 4 + t] = v;
  }
  __syncthreads();
  const int lane = t & 63;
  const int l31 = lane & 31, hi = lane >> 5;
  const int osub = l31 >> 2, comp = l31 & 3, br = comp >> 1;
  const int o = mt * 8 + osub;
#pragma unroll 1
  for (int pass = 0; pass < 2; ++pass) {
    const int ks = pass * 12 + (t >> 6);
    f16x8 v;
#pragma unroll
    for (int j = 0; j < 8; ++j) {
      const int k = ks * 16 + hi * 8 + j;
      float f = 0.f;
      if (k < 2 * kH && o < kH) {
        const int i = k >> 1, kodd = k & 1;
        const int reim = kodd ? (1 - (comp & 1)) : (comp & 1);
        f = s[i][br][osub][reim];
        if (kodd && !(comp & 1)) f = -f;   // -w_im for real-output rows
      }
      v[j] = (f16)f;
    }
    *(f16x8*)&ws[(((size_t)(c * 2 + L) * kMT + mt) * kKS2 + ks) * 512 + lane * 8] = v;
  }
}

// ---- prep: final layer (16x16 path, unchanged)
__global__ __launch_bounds__(768) void prep_final(
    const int* __restrict__ model_idx, const float* __restrict__ Wf,
    f16* __restrict__ ws)
{
  const int c = blockIdx.x;
  const int m = model_idx[c];
  const int t = threadIdx.x;
  const int ks = t >> 6, lane = t & 63;
  const int kg = lane >> 4, col = lane & 15;
  f16x8 v;
#pragma unroll
  for (int j = 0; j < 8; ++j) {
    const int k = ks * 32 + kg * 8 + j;
    float f = 0.f;
    if (k < 2 * kH && col < kOut) {
      const int i = k >> 1;
      const float* p = &Wf[(((size_t)m * kH + i) * kOut + col) * 2];
      f = (k & 1) ? -p[1] : p[0];
    }
    v[j] = (f16)f;
  }
  *(f16x8*)&ws[kWfOff + ((size_t)c * kKS + ks) * 512 + lane * 8] = v;
}

// ---- prep: layer-0 A-frags (16x16 path, unchanged)
__global__ __launch_bounds__(256) void prep_l0(
    const int* __restrict__ model_idx,
    const float* __restrict__ W0a, const float* __restrict__ W0b,
    f16* __restrict__ ws)
{
  const int c = blockIdx.x;
  const int m = model_idx[c];
#pragma unroll 1
  for (int it = 0; it < 12; ++it) {
    const int slot = it * 256 + threadIdx.x;
    const int nt = slot >> 6, lane = slot & 63;
    const int kg = lane >> 4, l15 = lane & 15;
    const int osub = l15 >> 2, comp = l15 & 3;
    const int o = nt * 4 + osub;
    f16x8 v = {};
    if (kg == 0 && o < kH && (comp & 1) == 0) {
#pragma unroll
      for (int k = 0; k < 2; ++k) {
        const float f = (comp == 0) ? W0a[(m * 2 + k) * kH + o]
                                    : W0b[(m * 2 + k) * kH + o];
        v[k] = (f16)f;
      }
    }
    *(f16x8*)&ws[kW0Off + (size_t)c * kW0Stride + (size_t)slot * 8] = v;
  }
}

#define ISSUE2(WIN, J0) { WIN[0] = ap[(J0) * 64]; WIN[1] = ap[(J0 + 1) * 64]; }
#define SLOT32(WIN, KSB)                                                       \
  __builtin_amdgcn_sched_barrier(0);                                           \
  __builtin_amdgcn_s_setprio(1);                                               \
  _Pragma("unroll")                                                            \
  for (int k2 = 0; k2 < 2; ++k2) {                                             \
    acc0 = __builtin_amdgcn_mfma_f32_32x32x16_f16(WIN[k2], B[0][(KSB) + k2], acc0, 0, 0, 0); \
    acc1 = __builtin_amdgcn_mfma_f32_32x32x16_f16(WIN[k2], B[1][(KSB) + k2], acc1, 0, 0, 0); \
  }                                                                            \
  __builtin_amdgcn_s_setprio(0);                                               \
  __builtin_amdgcn_sched_barrier(0);

// ---- one hidden layer, IN PLACE, C^T, 32x32x16 MFMA (21% better FLOP/cyc,
// half the MFMA instructions vs 16x16x32 — m119). C/D layout: col=lane&31
// (point), regs 4g..4g+3 = comps 0..3 of neuron mt*8+2g+hi -> activation
// stays lane-local. B-hold 2x24 frags = 192 regs; acc 32; windows 24;
// bias quads 16 -> ~285 combined, inside the ~320 cap (r20/r22 calibrated).
__device__ __forceinline__ void hidden_gemm(
    char* __restrict__ X, const f16x8* __restrict__ wl,
    const float* __restrict__ bp,   // packed bias[q] f32x4 for this (c,L)
    int w, int lane)
{
  const int l31 = lane & 31, hi = lane >> 5;
  f16x8 B[2][kKS2];
#pragma unroll
  for (int pt = 0; pt < 2; ++pt)
#pragma unroll
    for (int ks = 0; ks < kKS2; ++ks)
      B[pt][ks] = *(const f16x8*)(X + xadr(l31 + 32 * pt, ks * 32 + hi * 16));
  __syncthreads();   // all waves hold X in regs; X may now be overwritten

  f16x8 A0[2], A1[2], A2[2];
  {
    const f16x8* ap = wl + (size_t)(w * 6) * (kKS2 * 64) + lane;
    ISSUE2(A0, 0)
    ISSUE2(A1, 2)
  }

#pragma unroll 1
  for (int mi = 0; mi < 6; ++mi) {
    const int mt = w * 6 + mi;
    const f16x8* ap = wl + (size_t)mt * (kKS2 * 64) + lane;
    // bias: 4 quads (neurons mt*8 + 2g + hi), issued early, branch-free
    f32x4 bv0 = *(const f32x4*)(bp + (size_t)(mt * 8 + 0 + hi) * 4);
    f32x4 bv1 = *(const f32x4*)(bp + (size_t)(mt * 8 + 2 + hi) * 4);
    f32x4 bv2 = *(const f32x4*)(bp + (size_t)(mt * 8 + 4 + hi) * 4);
    f32x4 bv3 = *(const f32x4*)(bp + (size_t)(mt * 8 + 6 + hi) * 4);
    f32x16 acc0 = {}, acc1 = {};
    ISSUE2(A2, 4)   SLOT32(A0, 0)
    ISSUE2(A0, 6)   SLOT32(A1, 2)
    ISSUE2(A1, 8)   SLOT32(A2, 4)
    ISSUE2(A2, 10)  SLOT32(A0, 6)
    ISSUE2(A0, 12)  SLOT32(A1, 8)
    ISSUE2(A1, 14)  SLOT32(A2, 10)
    ISSUE2(A2, 16)  SLOT32(A0, 12)
    ISSUE2(A0, 18)  SLOT32(A1, 14)
    ISSUE2(A1, 20)  SLOT32(A2, 16)
    ISSUE2(A2, 22)  SLOT32(A0, 18)
    ISSUE2(A0, 24)  SLOT32(A1, 20)   // issues next-mt ks0,1
    ISSUE2(A1, 26)  SLOT32(A2, 22)   // issues next-mt ks2,3 (mi=5 lookahead
                                     // lands in adjacent valid ws, unused)
    // lane-local Gabor activation: reg-quad g = comps of neuron mt*8+2g+hi
#pragma unroll
    for (int pt = 0; pt < 2; ++pt)
#pragma unroll
      for (int g = 0; g < 4; ++g) {
        const f32x4 bq = (g == 0) ? bv0 : (g == 1) ? bv1 : (g == 2) ? bv2 : bv3;
        const float v0 = (pt ? acc1 : acc0)[4 * g + 0] + bq[0];
        const float v1 = (pt ? acc1 : acc0)[4 * g + 1] + bq[1];
        const float v2 = (pt ? acc1 : acc0)[4 * g + 2] + bq[2];
        const float v3 = (pt ? acc1 : acc0)[4 * g + 3] + bq[3];
        const float mag = kS2 * (v0 * v0 + v1 * v1 + v2 * v2 + v3 * v3);
        const float amp = __expf(fmaf(-kOmega, v1, -mag));
        const float ph  = kOmega * v0;
        f16x2 pv = {(f16)(amp * __cosf(ph)), (f16)(amp * __sinf(ph))};
        const int n = mt * 8 + g * 2 + hi;
        *(f16x2*)(X + xadr(l31 + 32 * pt, n * 4)) = pv;
      }
  }
}

__global__ __launch_bounds__(256, 2)
void wire_main(
    const float* __restrict__ inp, const int* __restrict__ indices,
    const int* __restrict__ model_idx, const int* __restrict__ bias_idx,
    const float* __restrict__ b0a, const float* __restrict__ b0b,
    const float* __restrict__ bf, const f16* __restrict__ wsW,
    float* __restrict__ out)
{
  __shared__ __align__(16) char X[kMB * kRowB];   // 49 KB single buffer
  const int d = blockIdx.x;
  const int lg = (d & 7) * 256 + (d >> 3);   // XCD swizzle (2048 % 8 == 0)
  const int c = lg >> 7;
  const int n0 = (lg & 127) * kMB;
  const int src = indices[c], m = model_idx[c], bix = bias_idx[c];
  const int tid = threadIdx.x, w = tid >> 6, lane = tid & 63;
  const int kg = lane >> 4, l15 = lane & 15;

  // ---- layer 0 as MFMA (16x16 C^T), pipelined 2-mi deep (r23)
  {
    f16x8 Bx[4];
#pragma unroll
    for (int pt = 0; pt < 4; ++pt) {
      const int row = l15 + 16 * pt;
      const float2 xv = *(const float2*)&inp[((size_t)src * kN + n0 + row) * 2];
      f16x8 b = {};
      if (kg == 0) { b[0] = (f16)xv.x; b[1] = (f16)xv.y; }
      Bx[pt] = b;
    }
    const f16x8* w0p = (const f16x8*)(wsW + kW0Off + (size_t)c * kW0Stride);
    const float* b0av = b0a + (size_t)bix * kH;
    const float* b0bv = b0b + (size_t)bix * kH;

    f16x8 aE, aO, aEn, aOn;
    float brE, crE, brO, crO, brEn, crEn, brOn, crOn;
    {
      const int ntE = w * 12, ntO = ntE + 1;
      aE = w0p[ntE * 64 + lane];
      aO = w0p[ntO * 64 + lane];
      const int qE = ntE * 4 + kg, qO = ntO * 4 + kg;
      brE = (qE < kH) ? b0av[qE] : 0.f;  crE = (qE < kH) ? b0bv[qE] : 0.f;
      brO = (qO < kH) ? b0av[qO] : 0.f;  crO = (qO < kH) ? b0bv[qO] : 0.f;
    }
#pragma unroll 1
    for (int it = 0; it < 6; ++it) {
      const int base = w * 12 + it * 2;
      {
        const int ntE = base + 2, ntO = base + 3;
        aEn = w0p[ntE * 64 + lane];
        aOn = w0p[ntO * 64 + lane];
        const int qE = ntE * 4 + kg, qO = ntO * 4 + kg;
        brEn = (qE < kH) ? b0av[qE] : 0.f;  crEn = (qE < kH) ? b0bv[qE] : 0.f;
        brOn = (qO < kH) ? b0av[qO] : 0.f;  crOn = (qO < kH) ? b0bv[qO] : 0.f;
      }
      __builtin_amdgcn_sched_barrier(0);
#pragma unroll
      for (int par = 0; par < 2; ++par) {
        const f16x8 a = par ? aO : aE;
        const float br_ = par ? brO : brE, cr_ = par ? crO : crE;
        const int q = (base + par) * 4 + kg;
        f32x4 acc[4] = {};
        __builtin_amdgcn_s_setprio(1);
        acc[0] = __builtin_amdgcn_mfma_f32_16x16x32_f16(a, Bx[0], acc[0], 0, 0, 0);
        acc[1] = __builtin_amdgcn_mfma_f32_16x16x32_f16(a, Bx[1], acc[1], 0, 0, 0);
        acc[2] = __builtin_amdgcn_mfma_f32_16x16x32_f16(a, Bx[2], acc[2], 0, 0, 0);
        acc[3] = __builtin_amdgcn_mfma_f32_16x16x32_f16(a, Bx[3], acc[3], 0, 0, 0);
        __builtin_amdgcn_s_setprio(0);
#pragma unroll
        for (int pt = 0; pt < 4; ++pt) {
          const float v0 = acc[pt][0] + br_;
          const float v2 = acc[pt][2] + cr_;
          const float mag = kS2 * (v0 * v0 + v2 * v2);
          const float amp = __expf(-mag);
          const float ph  = kOmega * v0;
          f16x2 pv = {(f16)(amp * __cosf(ph)), (f16)(amp * __sinf(ph))};
          *(f16x2*)(&X[0] + xadr(l15 + 16 * pt, q * 4)) = pv;
        }
      }
      __builtin_amdgcn_sched_barrier(0);
      aE = aEn; aO = aOn;
      brE = brEn; crE = crEn; brO = brOn; crO = crOn;
    }
  }
  __syncthreads();
  const float* biasB = (const float*)(wsW + kBiasOff);
  hidden_gemm(X, (const f16x8*)(wsW + (size_t)(c * 2 + 0) * kWLayerStride),
              biasB + (size_t)(c * 2 + 0) * 192 * 4, w, lane);
  __syncthreads();
  hidden_gemm(X, (const f16x8*)(wsW + (size_t)(c * 2 + 1) * kWLayerStride),
              biasB + (size_t)(c * 2 + 1) * 192 * 4, w, lane);
  __syncthreads();
  // ---- final complex 181->3 (16x16 path), wf batch-loaded (r23)
  {
    const f16x8* wf = (const f16x8*)(wsW + kWfOff + (size_t)c * kWfStride);
    f16x8 wfr[kKS];
#pragma unroll
    for (int ks = 0; ks < kKS; ++ks) wfr[ks] = wf[(size_t)ks * 64 + lane];
    __builtin_amdgcn_sched_barrier(0);
    f32x4 facc = {0.f, 0.f, 0.f, 0.f};
#pragma unroll
    for (int ks = 0; ks < kKS; ++ks) {
      f16x8 a = *(const f16x8*)(&X[0] + xadr(l15 + 16 * w, ks * 64 + kg * 16));
      facc = __builtin_amdgcn_mfma_f32_16x16x32_f16(a, wfr[ks], facc, 0, 0, 0);
    }
    if (l15 < kOut) {
      const float bfr = bf[(bix * kOut + l15) * 2];
#pragma unroll
      for (int j = 0; j < 4; ++j) {
        const int row = w * 16 + kg * 4 + j;
        out[((size_t)c * kN + n0 + row) * kOut + l15] = facc[j] + bfr;
      }
    }
  }
}

}  // namespace

extern "C" void kernel_launch(void* const* d_in, const int* in_sizes, int n_in,
                              void* d_out, int out_size, void* d_ws, size_t ws_size,
                              hipStream_t stream) {
  const float* inp       = (const float*)d_in[0];
  const int*   indices   = (const int*)  d_in[1];
  const int*   model_idx = (const int*)  d_in[2];
  const int*   bias_idx  = (const int*)  d_in[3];
  const float* W0a = (const float*)d_in[4];
  const float* b0a = (const float*)d_in[5];
  const float* W0b = (const float*)d_in[6];
  const float* b0b = (const float*)d_in[7];
  const float* W1a = (const float*)d_in[8];
  const float* b1a = (const float*)d_in[9];
  const float* W1b = (const float*)d_in[10];
  const float* b1b = (const float*)d_in[11];
  const float* W2a = (const float*)d_in[12];
  const float* b2a = (const float*)d_in[13];
  const float* W2b = (const float*)d_in[14];
  const float* b2b = (const float*)d_in[15];
  const float* Wf  = (const float*)d_in[16];
  const float* bff = (const float*)d_in[17];
  f16*   ws  = (f16*)d_ws;     // needs ~20.0 MB
  float* out = (float*)d_out;

  prep_hidden<<<dim3(kC * 2 * kMT), dim3(768), 0, stream>>>(
      model_idx, bias_idx, W1a, W1b, W2a, W2b, b1a, b1b, b2a, b2b, ws);
  prep_final<<<dim3(kC), dim3(768), 0, stream>>>(model_idx, Wf, ws);
  prep_l0<<<dim3(kC), dim3(256), 0, stream>>>(model_idx, W0a, W0b, ws);
  wire_main<<<dim3(kC * (kN / kMB)), dim3(256), 0, stream>>>(
      inp, indices, model_idx, bias_idx, b0a, b0b,
      bff, ws, out);
}

// Round 25
// 182.242 us; speedup vs baseline: 1.3304x; 1.3304x over previous
//
#include <hip/hip_runtime.h>

typedef _Float16 f16;
typedef _Float16 f16x2 __attribute__((ext_vector_type(2)));
typedef _Float16 f16x8 __attribute__((ext_vector_type(8)));
typedef float f32x4 __attribute__((ext_vector_type(4)));

namespace {

constexpr int kC = 16, kN = 8192, kH = 181, kOut = 3;
constexpr int kMB = 64;            // points per block (4-tile B-hold)
constexpr int kKpad = 384;         // 12 ksteps * 32
constexpr int kNT = 48;            // tiles of 16 output-comps (4 neurons each)
constexpr int kKS = 12;            // k-steps of 32
constexpr int kRowB = 784;         // 768 data bytes + 16B pad (bank spread)
constexpr float kOmega = 30.f, kS2 = 100.f;

constexpr size_t kWLayerStride = (size_t)kNT * kKS * 64 * 8;  // f16 per (c,layer)
constexpr size_t kWfOff = kWLayerStride * kC * 2;             // f16 elems
constexpr size_t kWfStride = (size_t)kKS * 64 * 8;
constexpr size_t kW0Off = kWfOff + (size_t)kC * kWfStride;    // layer-0 frags
constexpr size_t kW0Stride = (size_t)kNT * 64 * 8;            // per c
constexpr size_t kBiasOff = kW0Off + (size_t)kC * kW0Stride;  // f16 units; packed
                                   // bias[c][L][q<192] f32x4 (re_a,im_a,re_b,im_b)

__device__ __forceinline__ int xadr(int row, int colb) { return row * kRowB + colb; }

// ---- prep: pack hidden-layer complex weights into fp16 fragment order
// ws[c][L][nt][ks][lane][8]; ALSO packs this (c,L,nt)'s 4 neurons' bias as
// f32x4[q] (zero-padded q>=181) so the main kernel loads bias with ONE
// dwordx4, branch-free, early.
__global__ __launch_bounds__(768) void prep_hidden(
    const int* __restrict__ model_idx, const int* __restrict__ bias_idx,
    const float* __restrict__ W1a, const float* __restrict__ W1b,
    const float* __restrict__ W2a, const float* __restrict__ W2b,
    const float* __restrict__ b1a, const float* __restrict__ b1b,
    const float* __restrict__ b2a, const float* __restrict__ b2b,
    f16* __restrict__ ws)
{
  __shared__ float s[kH][2][4][2];   // [i][branch][o_sub][reim]
  const int bid = blockIdx.x;
  const int c  = bid / (2 * kNT);
  const int L  = (bid / kNT) % 2;
  const int nt = bid % kNT;
  const int m  = model_idx[c];
  const float* Wa = (L == 0 ? W1a : W2a) + (size_t)m * kH * kH * 2;
  const float* Wb = (L == 0 ? W1b : W2b) + (size_t)m * kH * kH * 2;
  const int t = threadIdx.x;
  if (t < 2 * kH) {
    const int i = t >> 1, br = t & 1;
    const float* src = (br ? Wb : Wa) + ((size_t)i * kH + nt * 4) * 2;
#pragma unroll
    for (int e = 0; e < 8; ++e) {
      const int osub = e >> 1, reim = e & 1;
      s[i][br][osub][reim] = (nt * 4 + osub < kH) ? src[osub * 2 + reim] : 0.f;
    }
  }
  // bias pack: t<16 covers (osub = t>>2, comp j = t&3)
  if (t < 16) {
    const int bix = bias_idx[c];
    const float* pa = (L == 0 ? b1a : b2a) + (size_t)bix * kH * 2;
    const float* pb = (L == 0 ? b1b : b2b) + (size_t)bix * kH * 2;
    const int osub = t >> 2, j = t & 3;
    const int q = nt * 4 + osub;
    float v = 0.f;
    if (q < kH) v = (j < 2) ? pa[q * 2 + j] : pb[q * 2 + (j - 2)];
    float* fb = (float*)(ws + kBiasOff);
    fb[((size_t)(c * 2 + L) * 192 + nt * 4) * 4 + t] = v;
  }
  __syncthreads();
  const int ks = t >> 6, lane = t & 63;
  const int kg = lane >> 4, l15 = lane & 15;
  const int osub = l15 >> 2, comp = l15 & 3, br = comp >> 1;
  const int o = nt * 4 + osub;
  f16x8 v;
#pragma unroll
  for (int j = 0; j < 8; ++j) {
    const int k = ks * 32 + kg * 8 + j;
    float f = 0.f;
    if (k < 2 * kH && o < kH) {
      const int i = k >> 1, kodd = k & 1;
      const int reim = kodd ? (1 - (comp & 1)) : (comp & 1);
      f = s[i][br][osub][reim];
      if (kodd && !(comp & 1)) f = -f;   // -w_im for real-output rows
    }
    v[j] = (f16)f;
  }
  *(f16x8*)&ws[(((size_t)(c * 2 + L) * kNT + nt) * kKS + ks) * 512 + lane * 8] = v;
}

// ---- prep: final layer (real part): col j<3, k=2i -> wf_re, 2i+1 -> -wf_im
__global__ __launch_bounds__(768) void prep_final(
    const int* __restrict__ model_idx, const float* __restrict__ Wf,
    f16* __restrict__ ws)
{
  const int c = blockIdx.x;
  const int m = model_idx[c];
  const int t = threadIdx.x;
  const int ks = t >> 6, lane = t & 63;
  const int kg = lane >> 4, col = lane & 15;
  f16x8 v;
#pragma unroll
  for (int j = 0; j < 8; ++j) {
    const int k = ks * 32 + kg * 8 + j;
    float f = 0.f;
    if (k < 2 * kH && col < kOut) {
      const int i = k >> 1;
      const float* p = &Wf[(((size_t)m * kH + i) * kOut + col) * 2];
      f = (k & 1) ? -p[1] : p[0];
    }
    v[j] = (f16)f;
  }
  *(f16x8*)&ws[kWfOff + ((size_t)c * kKS + ks) * 512 + lane * 8] = v;
}

// ---- prep: layer-0 A-frags. One K=32 tile, only k=0,1 valid.
// comp rows: (W0a[k][o], 0, W0b[k][o], 0) -> acc = (la, 0, lb, 0).
__global__ __launch_bounds__(256) void prep_l0(
    const int* __restrict__ model_idx,
    const float* __restrict__ W0a, const float* __restrict__ W0b,
    f16* __restrict__ ws)
{
  const int c = blockIdx.x;
  const int m = model_idx[c];
#pragma unroll 1
  for (int it = 0; it < 12; ++it) {
    const int slot = it * 256 + threadIdx.x;   // 48 nt x 64 lanes
    const int nt = slot >> 6, lane = slot & 63;
    const int kg = lane >> 4, l15 = lane & 15;
    const int osub = l15 >> 2, comp = l15 & 3;
    const int o = nt * 4 + osub;
    f16x8 v = {};
    if (kg == 0 && o < kH && (comp & 1) == 0) {
#pragma unroll
      for (int k = 0; k < 2; ++k) {
        const float f = (comp == 0) ? W0a[(m * 2 + k) * kH + o]
                                    : W0b[(m * 2 + k) * kH + o];
        v[k] = (f16)f;
      }
    }
    *(f16x8*)&ws[kW0Off + (size_t)c * kW0Stride + (size_t)slot * 8] = v;
  }
}

// issue 2 A-frags into a named window; consume 2 ks of a window (8 MFMAs).
#define ISSUE2(WIN, J0) { WIN[0] = ap[(J0) * 64]; WIN[1] = ap[(J0 + 1) * 64]; }
#define SLOT2(WIN, KSB)                                                        \
  __builtin_amdgcn_sched_barrier(0);                                           \
  __builtin_amdgcn_s_setprio(1);                                               \
  _Pragma("unroll")                                                            \
  for (int k2 = 0; k2 < 2; ++k2) {                                             \
    acc[0] = __builtin_amdgcn_mfma_f32_16x16x32_f16(WIN[k2], B[0][(KSB) + k2], acc[0], 0, 0, 0); \
    acc[1] = __builtin_amdgcn_mfma_f32_16x16x32_f16(WIN[k2], B[1][(KSB) + k2], acc[1], 0, 0, 0); \
    acc[2] = __builtin_amdgcn_mfma_f32_16x16x32_f16(WIN[k2], B[2][(KSB) + k2], acc[2], 0, 0, 0); \
    acc[3] = __builtin_amdgcn_mfma_f32_16x16x32_f16(WIN[k2], B[3][(KSB) + k2], acc[3], 0, 0, 0); \
  }                                                                            \
  __builtin_amdgcn_s_setprio(0);                                               \
  __builtin_amdgcn_sched_barrier(0);

// ---- one hidden layer, IN PLACE, C^T, P=64, three-window pair rotation.
// B-hold 192 AGPR; windows 24 VGPR; issue-to-consume distance 2 slots.
__device__ __forceinline__ void hidden_gemm(
    char* __restrict__ X, const f16x8* __restrict__ wl,
    const float* __restrict__ bp,   // packed bias[q] f32x4 for this (c,L)
    int w, int lane)
{
  const int kg = lane >> 4, l15 = lane & 15;
  f16x8 B[4][kKS];
#pragma unroll
  for (int pt = 0; pt < 4; ++pt)
#pragma unroll
    for (int ks = 0; ks < kKS; ++ks)
      B[pt][ks] = *(const f16x8*)(X + xadr(l15 + 16 * pt, ks * 64 + kg * 16));
  __syncthreads();   // all waves hold X in regs; X may now be overwritten

  f16x8 A0[2], A1[2], A2[2];
  {  // prologue: windows 0,1 of mi=0 (ks0-3)
    const f16x8* ap = wl + (size_t)(w * 12) * (kKS * 64) + lane;
    ISSUE2(A0, 0)
    ISSUE2(A1, 2)
  }

#pragma unroll 1
  for (int mi = 0; mi < 12; ++mi) {
    const int nt = w * 12 + mi;
    const int q = nt * 4 + kg;           // this lane's neuron
    const f16x8* ap = wl + (size_t)nt * (kKS * 64) + lane;
    // bias: one early branch-free load; lands during the 6 slots
    const f32x4 bv = *(const f32x4*)(bp + (size_t)q * 4);
    f32x4 acc[4] = {};
    ISSUE2(A2, 4)   SLOT2(A0, 0)    // consume ks0,1 (issued 2 slots ago)
    ISSUE2(A0, 6)   SLOT2(A1, 2)
    ISSUE2(A1, 8)   SLOT2(A2, 4)
    ISSUE2(A2, 10)  SLOT2(A0, 6)
    ISSUE2(A0, 12)  SLOT2(A1, 8)    // issues next-mi ks0,1
    ISSUE2(A1, 14)  SLOT2(A2, 10)   // issues next-mi ks2,3
    // lane-local Gabor activation; overlaps the in-flight next-mi windows.
#pragma unroll
    for (int pt = 0; pt < 4; ++pt) {
      const float v0 = acc[pt][0] + bv[0], v1 = acc[pt][1] + bv[1];
      const float v2 = acc[pt][2] + bv[2], v3 = acc[pt][3] + bv[3];
      const float mag = kS2 * (v0 * v0 + v1 * v1 + v2 * v2 + v3 * v3);
      const float amp = __expf(fmaf(-kOmega, v1, -mag));
      const float ph  = kOmega * v0;
      f16x2 pv = {(f16)(amp * __cosf(ph)), (f16)(amp * __sinf(ph))};
      *(f16x2*)(X + xadr(l15 + 16 * pt, q * 4)) = pv;
    }
  }
}

__global__ __launch_bounds__(256, 2)   // B 192 (AGPR) + windows 24 + acc 16
void wire_main(
    const float* __restrict__ inp, const int* __restrict__ indices,
    const int* __restrict__ model_idx, const int* __restrict__ bias_idx,
    const float* __restrict__ b0a, const float* __restrict__ b0b,
    const float* __restrict__ bf, const f16* __restrict__ wsW,
    float* __restrict__ out)
{
  __shared__ __align__(16) char X[kMB * kRowB];   // 49 KB single buffer
  const int d = blockIdx.x;
  const int lg = (d & 7) * 256 + (d >> 3);   // XCD swizzle (2048 % 8 == 0)
  const int c = lg >> 7;                     // 128 blocks per c
  const int n0 = (lg & 127) * kMB;
  const int src = indices[c], m = model_idx[c], bix = bias_idx[c];
  const int tid = threadIdx.x, w = tid >> 6, lane = tid & 63;
  const int kg = lane >> 4, l15 = lane & 15;

  // ---- layer 0 as MFMA (C^T), software-pipelined one iteration deep:
  // 2 mi per loop iteration; mi+2/mi+3's A-frag+bias issued at the top.
  {
    f16x8 Bx[4];
#pragma unroll
    for (int pt = 0; pt < 4; ++pt) {
      const int row = l15 + 16 * pt;
      const float2 xv = *(const float2*)&inp[((size_t)src * kN + n0 + row) * 2];
      f16x8 b = {};
      if (kg == 0) { b[0] = (f16)xv.x; b[1] = (f16)xv.y; }
      Bx[pt] = b;
    }
    const f16x8* w0p = (const f16x8*)(wsW + kW0Off + (size_t)c * kW0Stride);
    const float* b0av = b0a + (size_t)bix * kH;
    const float* b0bv = b0b + (size_t)bix * kH;

    f16x8 aE, aO, aEn, aOn;
    float brE, crE, brO, crO, brEn, crEn, brOn, crOn;
    {  // prologue: mi 0,1
      const int ntE = w * 12, ntO = ntE + 1;
      aE = w0p[ntE * 64 + lane];
      aO = w0p[ntO * 64 + lane];
      const int qE = ntE * 4 + kg, qO = ntO * 4 + kg;
      brE = (qE < kH) ? b0av[qE] : 0.f;  crE = (qE < kH) ? b0bv[qE] : 0.f;
      brO = (qO < kH) ? b0av[qO] : 0.f;  crO = (qO < kH) ? b0bv[qO] : 0.f;
    }
#pragma unroll 1
    for (int it = 0; it < 6; ++it) {
      const int base = w * 12 + it * 2;
      // issue mi base+2, base+3 (it=5 lookahead lands in adjacent valid ws /
      // is q<kH-guarded for bias; never consumed)
      {
        const int ntE = base + 2, ntO = base + 3;
        aEn = w0p[ntE * 64 + lane];
        aOn = w0p[ntO * 64 + lane];
        const int qE = ntE * 4 + kg, qO = ntO * 4 + kg;
        brEn = (qE < kH) ? b0av[qE] : 0.f;  crEn = (qE < kH) ? b0bv[qE] : 0.f;
        brOn = (qO < kH) ? b0av[qO] : 0.f;  crOn = (qO < kH) ? b0bv[qO] : 0.f;
      }
      __builtin_amdgcn_sched_barrier(0);
#pragma unroll
      for (int par = 0; par < 2; ++par) {
        const f16x8 a = par ? aO : aE;
        const float br_ = par ? brO : brE, cr_ = par ? crO : crE;
        const int q = (base + par) * 4 + kg;
        f32x4 acc[4] = {};
        __builtin_amdgcn_s_setprio(1);
        acc[0] = __builtin_amdgcn_mfma_f32_16x16x32_f16(a, Bx[0], acc[0], 0, 0, 0);
        acc[1] = __builtin_amdgcn_mfma_f32_16x16x32_f16(a, Bx[1], acc[1], 0, 0, 0);
        acc[2] = __builtin_amdgcn_mfma_f32_16x16x32_f16(a, Bx[2], acc[2], 0, 0, 0);
        acc[3] = __builtin_amdgcn_mfma_f32_16x16x32_f16(a, Bx[3], acc[3], 0, 0, 0);
        __builtin_amdgcn_s_setprio(0);
#pragma unroll
        for (int pt = 0; pt < 4; ++pt) {
          const float v0 = acc[pt][0] + br_;
          const float v2 = acc[pt][2] + cr_;
          const float mag = kS2 * (v0 * v0 + v2 * v2);
          const float amp = __expf(-mag);
          const float ph  = kOmega * v0;
          f16x2 pv = {(f16)(amp * __cosf(ph)), (f16)(amp * __sinf(ph))};
          *(f16x2*)(&X[0] + xadr(l15 + 16 * pt, q * 4)) = pv;
        }
      }
      __builtin_amdgcn_sched_barrier(0);
      // rotate state (static copies; load latency already hidden)
      aE = aEn; aO = aOn;
      brE = brEn; crE = crEn; brO = brOn; crO = crOn;
    }
  }
  __syncthreads();
  const float* biasB = (const float*)(wsW + kBiasOff);
  hidden_gemm(X, (const f16x8*)(wsW + (size_t)(c * 2 + 0) * kWLayerStride),
              biasB + (size_t)(c * 2 + 0) * 192 * 4, w, lane);
  __syncthreads();
  hidden_gemm(X, (const f16x8*)(wsW + (size_t)(c * 2 + 1) * kWLayerStride),
              biasB + (size_t)(c * 2 + 1) * 192 * 4, w, lane);
  __syncthreads();
  // ---- final complex 181->3, real part; wave w owns point-tile w.
  // wf frags batch-loaded (registers free here) so the 12 loads overlap.
  {
    const f16x8* wf = (const f16x8*)(wsW + kWfOff + (size_t)c * kWfStride);
    f16x8 wfr[kKS];
#pragma unroll
    for (int ks = 0; ks < kKS; ++ks) wfr[ks] = wf[(size_t)ks * 64 + lane];
    __builtin_amdgcn_sched_barrier(0);
    f32x4 facc = {0.f, 0.f, 0.f, 0.f};
#pragma unroll
    for (int ks = 0; ks < kKS; ++ks) {
      f16x8 a = *(const f16x8*)(&X[0] + xadr(l15 + 16 * w, ks * 64 + kg * 16));
      facc = __builtin_amdgcn_mfma_f32_16x16x32_f16(a, wfr[ks], facc, 0, 0, 0);
    }
    if (l15 < kOut) {
      const float bfr = bf[(bix * kOut + l15) * 2];
#pragma unroll
      for (int j = 0; j < 4; ++j) {
        const int row = w * 16 + kg * 4 + j;
        out[((size_t)c * kN + n0 + row) * kOut + l15] = facc[j] + bfr;
      }
    }
  }
}

}  // namespace

extern "C" void kernel_launch(void* const* d_in, const int* in_sizes, int n_in,
                              void* d_out, int out_size, void* d_ws, size_t ws_size,
                              hipStream_t stream) {
  const float* inp       = (const float*)d_in[0];
  const int*   indices   = (const int*)  d_in[1];
  const int*   model_idx = (const int*)  d_in[2];
  const int*   bias_idx  = (const int*)  d_in[3];
  const float* W0a = (const float*)d_in[4];
  const float* b0a = (const float*)d_in[5];
  const float* W0b = (const float*)d_in[6];
  const float* b0b = (const float*)d_in[7];
  const float* W1a = (const float*)d_in[8];
  const float* b1a = (const float*)d_in[9];
  const float* W1b = (const float*)d_in[10];
  const float* b1b = (const float*)d_in[11];
  const float* W2a = (const float*)d_in[12];
  const float* b2a = (const float*)d_in[13];
  const float* W2b = (const float*)d_in[14];
  const float* b2b = (const float*)d_in[15];
  const float* Wf  = (const float*)d_in[16];
  const float* bff = (const float*)d_in[17];
  f16*   ws  = (f16*)d_ws;     // needs ~20.0 MB
  float* out = (float*)d_out;

  prep_hidden<<<dim3(kC * 2 * kNT), dim3(768), 0, stream>>>(
      model_idx, bias_idx, W1a, W1b, W2a, W2b, b1a, b1b, b2a, b2b, ws);
  prep_final<<<dim3(kC), dim3(768), 0, stream>>>(model_idx, Wf, ws);
  prep_l0<<<dim3(kC), dim3(256), 0, stream>>>(model_idx, W0a, W0b, ws);
  wire_main<<<dim3(kC * (kN / kMB)), dim3(256), 0, stream>>>(
      inp, indices, model_idx, bias_idx, b0a, b0b,
      bff, ws, out);
}